// Round 4
// baseline (1035.883 us; speedup 1.0000x reference)
//
#include <hip/hip_runtime.h>
#include <hip/hip_fp16.h>

#define N_NODES 100000
#define N_EDGES 1600000
#define IN_C 64
#define HID_C 64
#define OUT_C 16

#define BKT 128        // nodes per dst bucket
#define BSH 7          // dst >> 7 = bucket
#define NBKT 782       // ceil(100000/128)
#define GB 128         // blocks in edge-binning passes
#define EPB 12500      // edges per binning block (128*12500 = 1.6M exact)
#define LM (NBKT*GB)   // count-matrix length = 100096

// ---------------------------------------------------------------------------
// Pass A1: per-block bucket histogram -> M[bucket*GB + block]
// ---------------------------------------------------------------------------
__global__ __launch_bounds__(512) void k_count(const int* __restrict__ dst,
                                               int* __restrict__ M) {
  __shared__ int h[NBKT];
  for (int i = threadIdx.x; i < NBKT; i += 512) h[i] = 0;
  __syncthreads();
  int base = blockIdx.x * EPB;
  int end = base + EPB;
  for (int e = base + threadIdx.x; e < end; e += 512)
    atomicAdd(&h[dst[e] >> BSH], 1);
  __syncthreads();
  for (int i = threadIdx.x; i < NBKT; i += 512) M[i * GB + blockIdx.x] = h[i];
}

// ---------------------------------------------------------------------------
// Generic 3-kernel exclusive scan (L=100096, nb=391 <= 512)
// ---------------------------------------------------------------------------
__global__ __launch_bounds__(256) void gscan_a(const int* __restrict__ in,
                                               int* __restrict__ bsum, int L) {
  __shared__ int s[256];
  int i = blockIdx.x * 256 + threadIdx.x;
  s[threadIdx.x] = (i < L) ? in[i] : 0;
  __syncthreads();
  for (int st = 128; st > 0; st >>= 1) {
    if (threadIdx.x < st) s[threadIdx.x] += s[threadIdx.x + st];
    __syncthreads();
  }
  if (threadIdx.x == 0) bsum[blockIdx.x] = s[0];
}

__global__ __launch_bounds__(512) void gscan_b(int* __restrict__ bsum, int nb) {
  __shared__ int s[512];
  int t = threadIdx.x;
  int v = (t < nb) ? bsum[t] : 0;
  s[t] = v;
  __syncthreads();
  for (int st = 1; st < 512; st <<= 1) {
    int a = (t >= st) ? s[t - st] : 0;
    __syncthreads();
    s[t] += a;
    __syncthreads();
  }
  if (t < nb) bsum[t] = s[t] - v;  // exclusive
}

__global__ __launch_bounds__(256) void gscan_c(const int* __restrict__ in,
                                               const int* __restrict__ bsum,
                                               int* __restrict__ outEx, int L) {
  __shared__ int s[256];
  int t = threadIdx.x;
  int i = blockIdx.x * 256 + t;
  int v = (i < L) ? in[i] : 0;
  s[t] = v;
  __syncthreads();
  for (int st = 1; st < 256; st <<= 1) {
    int a = (t >= st) ? s[t - st] : 0;
    __syncthreads();
    s[t] += a;
    __syncthreads();
  }
  if (i < L) outEx[i] = s[t] - v + bsum[blockIdx.x];
}

// ---------------------------------------------------------------------------
// Pass A2: scatter edges into bucket-binned array. Each (bucket,block)
// segment is contiguous -> frontier writes are line-dense. (src<<7)|dst_local.
// ---------------------------------------------------------------------------
__global__ __launch_bounds__(512) void k_binscatter(
    const int* __restrict__ src, const int* __restrict__ dst,
    const int* __restrict__ Mex, int* __restrict__ binned) {
  __shared__ int cur[NBKT];
  for (int i = threadIdx.x; i < NBKT; i += 512)
    cur[i] = Mex[i * GB + blockIdx.x];
  __syncthreads();
  int base = blockIdx.x * EPB;
  int end = base + EPB;
  for (int e = base + threadIdx.x; e < end; e += 512) {
    int d = dst[e];
    int pos = atomicAdd(&cur[d >> BSH], 1);
    binned[pos] = (src[e] << BSH) | (d & (BKT - 1));
  }
}

// ---------------------------------------------------------------------------
// GEMM 1: p(fp16) = x @ Wl ; q(fp16) = x @ Wr + b   (M=100k, K=64, N=64+64)
// ---------------------------------------------------------------------------
__global__ __launch_bounds__(256) void k_gemm1(
    const float* __restrict__ x, const float* __restrict__ Wl,
    const float* __restrict__ Wr, const float* __restrict__ b,
    __half* __restrict__ p, __half* __restrict__ q) {
  __shared__ float sA[64 * 66];
  __shared__ float sW[64 * 128];
  int t = threadIdx.x;
  int n0 = blockIdx.x * 64;

  for (int i = t; i < 64 * 64; i += 256) {
    int r = i >> 6, c = i & 63;
    int n = n0 + r;
    sA[r * 66 + c] = (n < N_NODES) ? x[(size_t)n * 64 + c] : 0.0f;
  }
  for (int f = t; f < 2048; f += 256) {
    int k = f >> 5, c4 = f & 31;
    float4 w = (c4 < 16) ? *(const float4*)&Wl[k * 64 + c4 * 4]
                         : *(const float4*)&Wr[k * 64 + (c4 - 16) * 4];
    *(float4*)&sW[k * 128 + c4 * 4] = w;
  }
  __syncthreads();

  int tx = t & 15;
  int ty = t >> 4;
  float acc[4][8];
#pragma unroll
  for (int i = 0; i < 4; ++i)
#pragma unroll
    for (int j = 0; j < 8; ++j) acc[i][j] = 0.0f;

  for (int k = 0; k < 64; ++k) {
    float4 w0 = *(float4*)&sW[k * 128 + tx * 8];
    float4 w1 = *(float4*)&sW[k * 128 + tx * 8 + 4];
    float wv[8] = {w0.x, w0.y, w0.z, w0.w, w1.x, w1.y, w1.z, w1.w};
#pragma unroll
    for (int i = 0; i < 4; ++i) {
      float a = sA[(ty * 4 + i) * 66 + k];
#pragma unroll
      for (int j = 0; j < 8; ++j) acc[i][j] += a * wv[j];
    }
  }

#pragma unroll
  for (int i = 0; i < 4; ++i) {
    int n = n0 + ty * 4 + i;
    if (n >= N_NODES) break;
    if (tx < 8) {
      int c = tx * 8;
      union { __half h[8]; float4 f; } u;
#pragma unroll
      for (int j = 0; j < 8; ++j) u.h[j] = __float2half(acc[i][j]);
      *(float4*)&p[(size_t)n * 64 + c] = u.f;
    } else {
      int c = (tx - 8) * 8;
      union { __half h[8]; float4 f; } u;
#pragma unroll
      for (int j = 0; j < 8; ++j) u.h[j] = __float2half(acc[i][j] + b[c + j]);
      *(float4*)&q[(size_t)n * 64 + c] = u.f;
    }
  }
}

// ---------------------------------------------------------------------------
// Fuse 1: per-bucket LDS accumulate of p1[src] over binned edges, then
// h = relu(acc/deg + q1) in place over q1 (fp16).
// ---------------------------------------------------------------------------
__global__ __launch_bounds__(512) void k_fuse1(
    const __half* __restrict__ p1, const int* __restrict__ Mex,
    const int* __restrict__ binned, __half* __restrict__ q1h) {
  __shared__ float sacc[BKT * 64];  // 32 KB, bank = lane -> 2-way (free)
  __shared__ int sdeg[BKT];
  int t = threadIdx.x;
  int b = blockIdx.x;
  for (int i = t; i < BKT * 64; i += 512) sacc[i] = 0.0f;
  if (t < BKT) sdeg[t] = 0;
  __syncthreads();
  int start = Mex[b * GB];
  int end = (b == NBKT - 1) ? N_EDGES : Mex[(b + 1) * GB];
  int lane = t & 63, w = t >> 6;
  for (int i = start + w * 4; i < end; i += 32) {
    int i1 = (i + 1 < end) ? i + 1 : i;
    int i2 = (i + 2 < end) ? i + 2 : i;
    int i3 = (i + 3 < end) ? i + 3 : i;
    int v0 = binned[i], v1 = binned[i1], v2 = binned[i2], v3 = binned[i3];
    float f0 = __half2float(p1[(v0 >> BSH) * 64 + lane]);
    float f1 = __half2float(p1[(v1 >> BSH) * 64 + lane]);
    float f2 = __half2float(p1[(v2 >> BSH) * 64 + lane]);
    float f3 = __half2float(p1[(v3 >> BSH) * 64 + lane]);
    atomicAdd(&sacc[(v0 & (BKT - 1)) * 64 + lane], f0);
    if (i + 1 < end) atomicAdd(&sacc[(v1 & (BKT - 1)) * 64 + lane], f1);
    if (i + 2 < end) atomicAdd(&sacc[(v2 & (BKT - 1)) * 64 + lane], f2);
    if (i + 3 < end) atomicAdd(&sacc[(v3 & (BKT - 1)) * 64 + lane], f3);
    if (lane == 0) {
      atomicAdd(&sdeg[v0 & (BKT - 1)], 1);
      if (i + 1 < end) atomicAdd(&sdeg[v1 & (BKT - 1)], 1);
      if (i + 2 < end) atomicAdd(&sdeg[v2 & (BKT - 1)], 1);
      if (i + 3 < end) atomicAdd(&sdeg[v3 & (BKT - 1)], 1);
    }
  }
  __syncthreads();
  for (int r = w; r < BKT; r += 8) {
    int n = b * BKT + r;
    if (n < N_NODES) {
      float inv = 1.0f / fmaxf((float)sdeg[r], 1.0f);
      size_t o = (size_t)n * 64 + lane;
      float qv = __half2float(q1h[o]);
      q1h[o] = __float2half(fmaxf(sacc[r * 64 + lane] * inv + qv, 0.0f));
    }
  }
}

// ---------------------------------------------------------------------------
// GEMM 2: p2(fp16) = h @ W2l ; q2(fp32) = h @ W2r + b2  (h is fp16)
// ---------------------------------------------------------------------------
__global__ __launch_bounds__(256) void k_gemm2(
    const __half* __restrict__ h, const float* __restrict__ Wl,
    const float* __restrict__ Wr, const float* __restrict__ b,
    __half* __restrict__ p, float* __restrict__ q) {
  __shared__ float sA[128 * 66];
  __shared__ float sW[64 * 32];
  int t = threadIdx.x;
  int n0 = blockIdx.x * 128;

  for (int i = t; i < 128 * 32; i += 256) {  // half2 units
    int r = i >> 5, c2 = i & 31;
    int n = n0 + r;
    float2 v = {0.0f, 0.0f};
    if (n < N_NODES) {
      __half2 hv = *(const __half2*)&h[(size_t)n * 64 + c2 * 2];
      v = __half22float2(hv);
    }
    sA[r * 66 + c2 * 2] = v.x;
    sA[r * 66 + c2 * 2 + 1] = v.y;
  }
  for (int f = t; f < 512; f += 256) {
    int k = f >> 3, c4 = f & 7;
    float4 w = (c4 < 4) ? *(const float4*)&Wl[k * 16 + c4 * 4]
                        : *(const float4*)&Wr[k * 16 + (c4 - 4) * 4];
    *(float4*)&sW[k * 32 + c4 * 4] = w;
  }
  __syncthreads();

  int tx = t & 7;
  int ty = t >> 3;
  float acc[4][4];
#pragma unroll
  for (int i = 0; i < 4; ++i)
#pragma unroll
    for (int j = 0; j < 4; ++j) acc[i][j] = 0.0f;

  for (int k = 0; k < 64; ++k) {
    float4 w = *(float4*)&sW[k * 32 + tx * 4];
    float wv[4] = {w.x, w.y, w.z, w.w};
#pragma unroll
    for (int i = 0; i < 4; ++i) {
      float a = sA[(ty * 4 + i) * 66 + k];
#pragma unroll
      for (int j = 0; j < 4; ++j) acc[i][j] += a * wv[j];
    }
  }

#pragma unroll
  for (int i = 0; i < 4; ++i) {
    int n = n0 + ty * 4 + i;
    if (n >= N_NODES) break;
    if (tx < 4) {
      int c = tx * 4;
      union { __half h[4]; float2 f; } u;
#pragma unroll
      for (int j = 0; j < 4; ++j) u.h[j] = __float2half(acc[i][j]);
      *(float2*)&p[(size_t)n * 16 + c] = u.f;
    } else {
      int c = (tx - 4) * 4;
      float4 o = {acc[i][0] + b[c], acc[i][1] + b[c + 1], acc[i][2] + b[c + 2],
                  acc[i][3] + b[c + 3]};
      *(float4*)&q[(size_t)n * 16 + c] = o;
    }
  }
}

// ---------------------------------------------------------------------------
// Fuse 2: per-bucket LDS accumulate of p2[src] (16 ch), out = acc/deg + q2.
// 16 lanes per edge, 4 edges per wave instruction.
// ---------------------------------------------------------------------------
__global__ __launch_bounds__(512) void k_fuse2(
    const __half* __restrict__ p2, const float* __restrict__ q2,
    const int* __restrict__ Mex, const int* __restrict__ binned,
    float* __restrict__ out) {
  __shared__ float sacc[BKT * 16];  // 8 KB
  __shared__ int sdeg[BKT];
  int t = threadIdx.x;
  int b = blockIdx.x;
  for (int i = t; i < BKT * 16; i += 512) sacc[i] = 0.0f;
  if (t < BKT) sdeg[t] = 0;
  __syncthreads();
  int start = Mex[b * GB];
  int end = (b == NBKT - 1) ? N_EDGES : Mex[(b + 1) * GB];
  int lane = t & 63, w = t >> 6;
  int sub = lane >> 4, c = lane & 15;
  for (int i = start + w * 4; i < end; i += 32) {
    int idx = i + sub;
    int idc = (idx < end) ? idx : (end - 1);
    int v = binned[idc];
    float f = __half2float(p2[(v >> BSH) * 16 + c]);
    if (idx < end) {
      atomicAdd(&sacc[(v & (BKT - 1)) * 16 + c], f);
      if (c == 0) atomicAdd(&sdeg[v & (BKT - 1)], 1);
    }
  }
  __syncthreads();
  for (int r4 = w * 4; r4 < BKT; r4 += 32) {
    int r = r4 + sub;
    int n = b * BKT + r;
    if (n < N_NODES) {
      float inv = 1.0f / fmaxf((float)sdeg[r], 1.0f);
      out[(size_t)n * 16 + c] = sacc[r * 16 + c] * inv + q2[(size_t)n * 16 + c];
    }
  }
}

extern "C" void kernel_launch(void* const* d_in, const int* in_sizes, int n_in,
                              void* d_out, int out_size, void* d_ws, size_t ws_size,
                              hipStream_t stream) {
  const float* x   = (const float*)d_in[0];
  const int* edge  = (const int*)d_in[1];
  const int* src   = edge;            // edge_index[0]
  const int* dst   = edge + N_EDGES;  // edge_index[1]
  const float* W1l = (const float*)d_in[2];
  const float* b1  = (const float*)d_in[3];
  const float* W1r = (const float*)d_in[4];
  const float* W2l = (const float*)d_in[5];
  const float* b2  = (const float*)d_in[6];
  const float* W2r = (const float*)d_in[7];
  float* out = (float*)d_out;

  // workspace layout
  int* M        = (int*)d_ws;          // 100096 (count matrix, scanned in place)
  int* bsum     = M + LM;              // 512
  int* binned   = bsum + 512;          // 1600000 (alive through fuse2)
  __half* p1    = (__half*)(binned + N_EDGES);   // 6.4M halves (12.8 MB)
  __half* q1h   = p1 + (size_t)N_NODES * 64;     // 6.4M halves (q1 -> h in place)
  __half* p2    = p1;                            // layer-2 reuse (p1 dead)
  float* q2     = (float*)(p1 + (size_t)N_NODES * 16);  // after p2 (3.2MB)

  int nbM = (LM + 255) / 256;          // 391

  // --- bin edges by dst bucket (no csr, no node-level scatter) ---
  k_count<<<GB, 512, 0, stream>>>(dst, M);
  gscan_a<<<nbM, 256, 0, stream>>>(M, bsum, LM);
  gscan_b<<<1, 512, 0, stream>>>(bsum, nbM);
  gscan_c<<<nbM, 256, 0, stream>>>(M, bsum, M, LM);  // in-place exclusive scan
  k_binscatter<<<GB, 512, 0, stream>>>(src, dst, M, binned);

  // --- layer 1 ---
  k_gemm1<<<(N_NODES + 63) / 64, 256, 0, stream>>>(x, W1l, W1r, b1, p1, q1h);
  k_fuse1<<<NBKT, 512, 0, stream>>>(p1, M, binned, q1h);

  // --- layer 2 ---
  k_gemm2<<<(N_NODES + 127) / 128, 256, 0, stream>>>(q1h, W2l, W2r, b2, p2, q2);
  k_fuse2<<<NBKT, 512, 0, stream>>>(p2, q2, M, binned, out);
}

// Round 5
// 310.559 us; speedup vs baseline: 3.3355x; 3.3355x over previous
//
#include <hip/hip_runtime.h>
#include <hip/hip_fp16.h>

#define N_NODES 100000
#define N_EDGES 1600000
#define IN_C 64
#define HID_C 64
#define OUT_C 16

#define BKT 256        // nodes per dst bucket
#define BSH 8          // dst >> 8 = bucket
#define NBKT 391       // ceil(100000/256)
#define GB 256         // blocks in edge-binning passes
#define EPB 6250       // edges per binning block (256*6250 = 1.6M exact)
#define LM (NBKT*GB)   // bucket count-matrix length = 100096
#define LTOT (LM + N_NODES)  // concatenated scan length = 200096
#define NB2 ((LTOT + 255) / 256)  // 782 scan blocks

// ---------------------------------------------------------------------------
// Pass A1: per-block bucket histogram -> S[bucket*GB + block], AND global
// per-node degree histogram -> S[LM + node] (int atomics, L2-resident).
// ---------------------------------------------------------------------------
__global__ __launch_bounds__(256) void k_count(const int* __restrict__ dst,
                                               int* __restrict__ S) {
  __shared__ int h[NBKT];
  for (int i = threadIdx.x; i < NBKT; i += 256) h[i] = 0;
  __syncthreads();
  int base = blockIdx.x * EPB;
  int end = base + EPB;
  for (int e = base + threadIdx.x; e < end; e += 256) {
    int d = dst[e];
    atomicAdd(&h[d >> BSH], 1);
    atomicAdd(&S[LM + d], 1);
  }
  __syncthreads();
  for (int i = threadIdx.x; i < NBKT; i += 256) S[i * GB + blockIdx.x] = h[i];
}

// ---------------------------------------------------------------------------
// Generic 3-kernel exclusive scan over the concatenated array (L=200096).
// Segment property: sum(S[0..LM)) == N_EDGES, so the second segment's scan
// equals N_EDGES + rowstart[n]. No separate node scan needed.
// ---------------------------------------------------------------------------
__global__ __launch_bounds__(256) void gscan_a(const int* __restrict__ in,
                                               int* __restrict__ bsum, int L) {
  __shared__ int s[256];
  int i = blockIdx.x * 256 + threadIdx.x;
  s[threadIdx.x] = (i < L) ? in[i] : 0;
  __syncthreads();
  for (int st = 128; st > 0; st >>= 1) {
    if (threadIdx.x < st) s[threadIdx.x] += s[threadIdx.x + st];
    __syncthreads();
  }
  if (threadIdx.x == 0) bsum[blockIdx.x] = s[0];
}

__global__ __launch_bounds__(1024) void gscan_b(int* __restrict__ bsum, int nb) {
  __shared__ int s[1024];
  int t = threadIdx.x;
  int v = (t < nb) ? bsum[t] : 0;
  s[t] = v;
  __syncthreads();
  for (int st = 1; st < 1024; st <<= 1) {
    int a = (t >= st) ? s[t - st] : 0;
    __syncthreads();
    s[t] += a;
    __syncthreads();
  }
  if (t < nb) bsum[t] = s[t] - v;  // exclusive
}

__global__ __launch_bounds__(256) void gscan_c(const int* __restrict__ in,
                                               const int* __restrict__ bsum,
                                               int* __restrict__ outEx, int L) {
  __shared__ int s[256];
  int t = threadIdx.x;
  int i = blockIdx.x * 256 + t;
  int v = (i < L) ? in[i] : 0;
  s[t] = v;
  __syncthreads();
  for (int st = 1; st < 256; st <<= 1) {
    int a = (t >= st) ? s[t - st] : 0;
    __syncthreads();
    s[t] += a;
    __syncthreads();
  }
  if (i < L) outEx[i] = s[t] - v + bsum[blockIdx.x];
}

// ---------------------------------------------------------------------------
// Pass A2: scatter edges into bucket-binned array (frontier writes are
// line-dense, L2-absorbed). Entry packs (src<<8)|dst_local.
// ---------------------------------------------------------------------------
__global__ __launch_bounds__(256) void k_binscatter(
    const int* __restrict__ src, const int* __restrict__ dst,
    const int* __restrict__ R, int* __restrict__ binned) {
  __shared__ int cur[NBKT];
  for (int i = threadIdx.x; i < NBKT; i += 256)
    cur[i] = R[i * GB + blockIdx.x];
  __syncthreads();
  int base = blockIdx.x * EPB;
  int end = base + EPB;
  for (int e = base + threadIdx.x; e < end; e += 256) {
    int d = dst[e];
    int pos = atomicAdd(&cur[d >> BSH], 1);
    binned[pos] = (src[e] << BSH) | (d & (BKT - 1));
  }
}

// Pass B: final scatter to CSR. Writes confined to this bucket's ~16KB span.
__global__ __launch_bounds__(256) void k_finalscatter(
    const int* __restrict__ binned, const int* __restrict__ R,
    int* __restrict__ csr) {
  int b = blockIdx.x;
  __shared__ int cur[BKT];
  int n = (b << BSH) + threadIdx.x;
  cur[threadIdx.x] = (n < N_NODES) ? (R[LM + n] - N_EDGES) : 0;
  __syncthreads();
  int start = R[b * GB];
  int end = (b == NBKT - 1) ? N_EDGES : R[(b + 1) * GB];
  for (int i = start + threadIdx.x; i < end; i += 256) {
    int v = binned[i];
    int pos = atomicAdd(&cur[v & (BKT - 1)], 1);
    csr[pos] = v >> BSH;
  }
}

// ---------------------------------------------------------------------------
// GEMM 1: p(fp16) = x @ Wl ; q(fp16) = x @ Wr + b   (M=100k, K=64, N=64+64)
// ---------------------------------------------------------------------------
__global__ __launch_bounds__(256) void k_gemm1(
    const float* __restrict__ x, const float* __restrict__ Wl,
    const float* __restrict__ Wr, const float* __restrict__ b,
    __half* __restrict__ p, __half* __restrict__ q) {
  __shared__ float sA[64 * 66];
  __shared__ float sW[64 * 128];
  int t = threadIdx.x;
  int n0 = blockIdx.x * 64;

  for (int i = t; i < 64 * 64; i += 256) {
    int r = i >> 6, c = i & 63;
    int n = n0 + r;
    sA[r * 66 + c] = (n < N_NODES) ? x[(size_t)n * 64 + c] : 0.0f;
  }
  for (int f = t; f < 2048; f += 256) {
    int k = f >> 5, c4 = f & 31;
    float4 w = (c4 < 16) ? *(const float4*)&Wl[k * 64 + c4 * 4]
                         : *(const float4*)&Wr[k * 64 + (c4 - 16) * 4];
    *(float4*)&sW[k * 128 + c4 * 4] = w;
  }
  __syncthreads();

  int tx = t & 15;
  int ty = t >> 4;
  float acc[4][8];
#pragma unroll
  for (int i = 0; i < 4; ++i)
#pragma unroll
    for (int j = 0; j < 8; ++j) acc[i][j] = 0.0f;

  for (int k = 0; k < 64; ++k) {
    float4 w0 = *(float4*)&sW[k * 128 + tx * 8];
    float4 w1 = *(float4*)&sW[k * 128 + tx * 8 + 4];
    float wv[8] = {w0.x, w0.y, w0.z, w0.w, w1.x, w1.y, w1.z, w1.w};
#pragma unroll
    for (int i = 0; i < 4; ++i) {
      float a = sA[(ty * 4 + i) * 66 + k];
#pragma unroll
      for (int j = 0; j < 8; ++j) acc[i][j] += a * wv[j];
    }
  }

#pragma unroll
  for (int i = 0; i < 4; ++i) {
    int n = n0 + ty * 4 + i;
    if (n >= N_NODES) break;
    if (tx < 8) {
      int c = tx * 8;
      union { __half h[8]; float4 f; } u;
#pragma unroll
      for (int j = 0; j < 8; ++j) u.h[j] = __float2half(acc[i][j]);
      *(float4*)&p[(size_t)n * 64 + c] = u.f;
    } else {
      int c = (tx - 8) * 8;
      union { __half h[8]; float4 f; } u;
#pragma unroll
      for (int j = 0; j < 8; ++j) u.h[j] = __float2half(acc[i][j] + b[c + j]);
      *(float4*)&q[(size_t)n * 64 + c] = u.f;
    }
  }
}

// ---------------------------------------------------------------------------
// Fuse 1: h[n] = relu(mean_j p1[csr_j] + q1[n]) in place over q1 (fp16).
// 32 lanes per node (half2 lanes), 8 nodes per 256-thread block.
// Each load instruction fetches a full 128B row; 4 outstanding per group.
// ---------------------------------------------------------------------------
__global__ __launch_bounds__(256) void k_fuse1(
    const __half2* __restrict__ p1, const int* __restrict__ R,
    const int* __restrict__ cnt, const int* __restrict__ csr,
    __half2* __restrict__ q1h) {
  int t = threadIdx.x;
  int n = blockIdx.x * 8 + (t >> 5);  // 12500*8 = 100000 exact
  int c2 = t & 31;
  int row = R[LM + n] - N_EDGES;
  int deg = cnt[n];
  float accx = 0.0f, accy = 0.0f;
  int j = 0;
  for (; j + 4 <= deg; j += 4) {
    int s0 = csr[row + j];
    int s1 = csr[row + j + 1];
    int s2 = csr[row + j + 2];
    int s3 = csr[row + j + 3];
    __half2 a0 = p1[s0 * 32 + c2];
    __half2 a1 = p1[s1 * 32 + c2];
    __half2 a2 = p1[s2 * 32 + c2];
    __half2 a3 = p1[s3 * 32 + c2];
    float2 f0 = __half22float2(a0);
    float2 f1 = __half22float2(a1);
    float2 f2 = __half22float2(a2);
    float2 f3 = __half22float2(a3);
    accx += (f0.x + f1.x) + (f2.x + f3.x);
    accy += (f0.y + f1.y) + (f2.y + f3.y);
  }
  for (; j < deg; ++j) {
    float2 f = __half22float2(p1[csr[row + j] * 32 + c2]);
    accx += f.x;
    accy += f.y;
  }
  float inv = 1.0f / fmaxf((float)deg, 1.0f);
  int o = n * 32 + c2;
  float2 qv = __half22float2(q1h[o]);
  float2 r;
  r.x = fmaxf(accx * inv + qv.x, 0.0f);
  r.y = fmaxf(accy * inv + qv.y, 0.0f);
  q1h[o] = __float22half2_rn(r);
}

// ---------------------------------------------------------------------------
// GEMM 2: p2(fp16) = h @ W2l ; q2(fp32) = h @ W2r + b2  (h is fp16)
// ---------------------------------------------------------------------------
__global__ __launch_bounds__(256) void k_gemm2(
    const __half* __restrict__ h, const float* __restrict__ Wl,
    const float* __restrict__ Wr, const float* __restrict__ b,
    __half* __restrict__ p, float* __restrict__ q) {
  __shared__ float sA[128 * 66];
  __shared__ float sW[64 * 32];
  int t = threadIdx.x;
  int n0 = blockIdx.x * 128;

  for (int i = t; i < 128 * 32; i += 256) {  // half2 units
    int r = i >> 5, c2 = i & 31;
    int n = n0 + r;
    float2 v = {0.0f, 0.0f};
    if (n < N_NODES) {
      __half2 hv = *(const __half2*)&h[(size_t)n * 64 + c2 * 2];
      v = __half22float2(hv);
    }
    sA[r * 66 + c2 * 2] = v.x;
    sA[r * 66 + c2 * 2 + 1] = v.y;
  }
  for (int f = t; f < 512; f += 256) {
    int k = f >> 3, c4 = f & 7;
    float4 w = (c4 < 4) ? *(const float4*)&Wl[k * 16 + c4 * 4]
                        : *(const float4*)&Wr[k * 16 + (c4 - 4) * 4];
    *(float4*)&sW[k * 32 + c4 * 4] = w;
  }
  __syncthreads();

  int tx = t & 7;
  int ty = t >> 3;
  float acc[4][4];
#pragma unroll
  for (int i = 0; i < 4; ++i)
#pragma unroll
    for (int j = 0; j < 4; ++j) acc[i][j] = 0.0f;

  for (int k = 0; k < 64; ++k) {
    float4 w = *(float4*)&sW[k * 32 + tx * 4];
    float wv[4] = {w.x, w.y, w.z, w.w};
#pragma unroll
    for (int i = 0; i < 4; ++i) {
      float a = sA[(ty * 4 + i) * 66 + k];
#pragma unroll
      for (int j = 0; j < 4; ++j) acc[i][j] += a * wv[j];
    }
  }

#pragma unroll
  for (int i = 0; i < 4; ++i) {
    int n = n0 + ty * 4 + i;
    if (n >= N_NODES) break;
    if (tx < 4) {
      int c = tx * 4;
      union { __half h[4]; float2 f; } u;
#pragma unroll
      for (int j = 0; j < 4; ++j) u.h[j] = __float2half(acc[i][j]);
      *(float2*)&p[(size_t)n * 16 + c] = u.f;
    } else {
      int c = (tx - 4) * 4;
      float4 o = {acc[i][0] + b[c], acc[i][1] + b[c + 1], acc[i][2] + b[c + 2],
                  acc[i][3] + b[c + 3]};
      *(float4*)&q[(size_t)n * 16 + c] = o;
    }
  }
}

// ---------------------------------------------------------------------------
// Fuse 2: out[n] = mean_j p2[csr_j] + q2[n].
// 8 lanes per node (half2 lanes), 32 nodes per 256-thread block.
// ---------------------------------------------------------------------------
__global__ __launch_bounds__(256) void k_fuse2(
    const __half2* __restrict__ p2, const float* __restrict__ q2,
    const int* __restrict__ R, const int* __restrict__ cnt,
    const int* __restrict__ csr, float* __restrict__ out) {
  int t = threadIdx.x;
  int n = blockIdx.x * 32 + (t >> 3);  // 3125*32 = 100000 exact
  int c2 = t & 7;
  int row = R[LM + n] - N_EDGES;
  int deg = cnt[n];
  float accx = 0.0f, accy = 0.0f;
  int j = 0;
  for (; j + 4 <= deg; j += 4) {
    int s0 = csr[row + j];
    int s1 = csr[row + j + 1];
    int s2 = csr[row + j + 2];
    int s3 = csr[row + j + 3];
    float2 f0 = __half22float2(p2[s0 * 8 + c2]);
    float2 f1 = __half22float2(p2[s1 * 8 + c2]);
    float2 f2 = __half22float2(p2[s2 * 8 + c2]);
    float2 f3 = __half22float2(p2[s3 * 8 + c2]);
    accx += (f0.x + f1.x) + (f2.x + f3.x);
    accy += (f0.y + f1.y) + (f2.y + f3.y);
  }
  for (; j < deg; ++j) {
    float2 f = __half22float2(p2[csr[row + j] * 8 + c2]);
    accx += f.x;
    accy += f.y;
  }
  float inv = 1.0f / fmaxf((float)deg, 1.0f);
  const float2* q2v = (const float2*)q2;
  float2 qv = q2v[n * 8 + c2];
  float2 r = {accx * inv + qv.x, accy * inv + qv.y};
  *(float2*)&out[(size_t)n * 16 + c2 * 2] = r;
}

extern "C" void kernel_launch(void* const* d_in, const int* in_sizes, int n_in,
                              void* d_out, int out_size, void* d_ws, size_t ws_size,
                              hipStream_t stream) {
  const float* x   = (const float*)d_in[0];
  const int* edge  = (const int*)d_in[1];
  const int* src   = edge;            // edge_index[0]
  const int* dst   = edge + N_EDGES;  // edge_index[1]
  const float* W1l = (const float*)d_in[2];
  const float* b1  = (const float*)d_in[3];
  const float* W1r = (const float*)d_in[4];
  const float* W2l = (const float*)d_in[5];
  const float* b2  = (const float*)d_in[6];
  const float* W2r = (const float*)d_in[7];
  float* out = (float*)d_out;

  // workspace layout (4-byte units; p1 base is 16B aligned)
  int* S      = (int*)d_ws;           // LTOT = 200096 (raw counts: M | deg)
  int* bsum   = S + LTOT;             // 1024
  int* R      = bsum + 1024;          // LTOT (scanned: bucket offs | N_EDGES+rowstart)
  int* binned = R + LTOT;             // 1600000
  int* csr    = binned + N_EDGES;     // 1600000
  __half* p1  = (__half*)(csr + N_EDGES);      // 6.4M halves (12.8 MB)
  __half* q1h = p1 + (size_t)N_NODES * 64;     // 6.4M halves (q1 -> h in place)
  __half* p2  = p1;                            // layer-2 reuse (p1 dead)
  float* q2   = (float*)(p1 + (size_t)N_NODES * 16);  // after p2 (3.2MB)
  int* cnt    = S + LM;               // raw node degrees

  hipMemsetAsync(cnt, 0, N_NODES * sizeof(int), stream);

  // --- CSR build: 6 dispatches ---
  k_count<<<GB, 256, 0, stream>>>(dst, S);
  gscan_a<<<NB2, 256, 0, stream>>>(S, bsum, LTOT);
  gscan_b<<<1, 1024, 0, stream>>>(bsum, NB2);
  gscan_c<<<NB2, 256, 0, stream>>>(S, bsum, R, LTOT);
  k_binscatter<<<GB, 256, 0, stream>>>(src, dst, R, binned);
  k_finalscatter<<<NBKT, 256, 0, stream>>>(binned, R, csr);

  // --- layer 1 ---
  k_gemm1<<<(N_NODES + 63) / 64, 256, 0, stream>>>(x, W1l, W1r, b1, p1, q1h);
  k_fuse1<<<N_NODES / 8, 256, 0, stream>>>((const __half2*)p1, R, cnt, csr,
                                           (__half2*)q1h);

  // --- layer 2 ---
  k_gemm2<<<(N_NODES + 127) / 128, 256, 0, stream>>>(q1h, W2l, W2r, b2, p2, q2);
  k_fuse2<<<N_NODES / 32, 256, 0, stream>>>((const __half2*)p2, q2, R, cnt, csr,
                                            out);
}

// Round 6
// 251.226 us; speedup vs baseline: 4.1233x; 1.2362x over previous
//
#include <hip/hip_runtime.h>
#include <hip/hip_fp16.h>

#define N_NODES 100000
#define N_EDGES 1600000
#define IN_C 64
#define HID_C 64
#define OUT_C 16

#define BKT 256        // nodes per dst bucket
#define BSH 8          // dst >> 8 = bucket
#define NBKT 391       // ceil(100000/256)
#define GB 256         // blocks in edge-binning passes
#define EPB 6250       // edges per binning block (256*6250 = 1.6M exact)
#define LM (NBKT*GB)   // bucket count-matrix length = 100096
#define NBM ((LM + 255) / 256)  // 391 scan blocks

// ---------------------------------------------------------------------------
// Pass A1: per-block bucket histogram -> S[bucket*GB + block]. LDS only.
// ---------------------------------------------------------------------------
__global__ __launch_bounds__(256) void k_count(const int* __restrict__ dst,
                                               int* __restrict__ S) {
  __shared__ int h[NBKT];
  for (int i = threadIdx.x; i < NBKT; i += 256) h[i] = 0;
  __syncthreads();
  int base = blockIdx.x * EPB;
  int end = base + EPB;
  for (int e = base + threadIdx.x; e < end; e += 256)
    atomicAdd(&h[dst[e] >> BSH], 1);
  __syncthreads();
  for (int i = threadIdx.x; i < NBKT; i += 256) S[i * GB + blockIdx.x] = h[i];
}

// ---------------------------------------------------------------------------
// Generic 3-kernel exclusive scan (L=100096, nb=391)
// ---------------------------------------------------------------------------
__global__ __launch_bounds__(256) void gscan_a(const int* __restrict__ in,
                                               int* __restrict__ bsum, int L) {
  __shared__ int s[256];
  int i = blockIdx.x * 256 + threadIdx.x;
  s[threadIdx.x] = (i < L) ? in[i] : 0;
  __syncthreads();
  for (int st = 128; st > 0; st >>= 1) {
    if (threadIdx.x < st) s[threadIdx.x] += s[threadIdx.x + st];
    __syncthreads();
  }
  if (threadIdx.x == 0) bsum[blockIdx.x] = s[0];
}

__global__ __launch_bounds__(512) void gscan_b(int* __restrict__ bsum, int nb) {
  __shared__ int s[512];
  int t = threadIdx.x;
  int v = (t < nb) ? bsum[t] : 0;
  s[t] = v;
  __syncthreads();
  for (int st = 1; st < 512; st <<= 1) {
    int a = (t >= st) ? s[t - st] : 0;
    __syncthreads();
    s[t] += a;
    __syncthreads();
  }
  if (t < nb) bsum[t] = s[t] - v;  // exclusive
}

__global__ __launch_bounds__(256) void gscan_c(const int* __restrict__ in,
                                               const int* __restrict__ bsum,
                                               int* __restrict__ outEx, int L) {
  __shared__ int s[256];
  int t = threadIdx.x;
  int i = blockIdx.x * 256 + t;
  int v = (i < L) ? in[i] : 0;
  s[t] = v;
  __syncthreads();
  for (int st = 1; st < 256; st <<= 1) {
    int a = (t >= st) ? s[t - st] : 0;
    __syncthreads();
    s[t] += a;
    __syncthreads();
  }
  if (i < L) outEx[i] = s[t] - v + bsum[blockIdx.x];
}

// ---------------------------------------------------------------------------
// Pass A2: scatter edges into bucket-binned array (frontier writes are
// line-dense, L2-absorbed). Entry packs (src<<8)|dst_local.
// ---------------------------------------------------------------------------
__global__ __launch_bounds__(256) void k_binscatter(
    const int* __restrict__ src, const int* __restrict__ dst,
    const int* __restrict__ R, int* __restrict__ binned) {
  __shared__ int cur[NBKT];
  for (int i = threadIdx.x; i < NBKT; i += 256)
    cur[i] = R[i * GB + blockIdx.x];
  __syncthreads();
  int base = blockIdx.x * EPB;
  int end = base + EPB;
  for (int e = base + threadIdx.x; e < end; e += 256) {
    int d = dst[e];
    int pos = atomicAdd(&cur[d >> BSH], 1);
    binned[pos] = (src[e] << BSH) | (d & (BKT - 1));
  }
}

// ---------------------------------------------------------------------------
// Pass B (fused): per-bucket node histogram -> LDS exclusive scan ->
// rowstart/cnt -> scatter binned segment to CSR. rowstart[first node of
// bucket] == R[b*GB] because CSR order is node-sorted and buckets are
// contiguous node ranges. No global atomics anywhere.
// ---------------------------------------------------------------------------
__global__ __launch_bounds__(256) void k_finalize(
    const int* __restrict__ binned, const int* __restrict__ R,
    int* __restrict__ csr, int* __restrict__ rowstart, int* __restrict__ cnt) {
  int b = blockIdx.x;
  __shared__ int hcnt[BKT];
  __shared__ int hscan[BKT];
  __shared__ int cur[BKT];
  int t = threadIdx.x;
  hcnt[t] = 0;
  __syncthreads();
  int start = R[b * GB];
  int end = (b == NBKT - 1) ? N_EDGES : R[(b + 1) * GB];
  for (int i = start + t; i < end; i += 256)
    atomicAdd(&hcnt[binned[i] & (BKT - 1)], 1);
  __syncthreads();
  int v = hcnt[t];
  hscan[t] = v;
  __syncthreads();
  for (int st = 1; st < 256; st <<= 1) {
    int a = (t >= st) ? hscan[t - st] : 0;
    __syncthreads();
    hscan[t] += a;
    __syncthreads();
  }
  int rs = start + hscan[t] - v;  // rowstart of node b*BKT + t
  cur[t] = rs;
  int n = (b << BSH) + t;
  if (n < N_NODES) {
    rowstart[n] = rs;
    cnt[n] = v;
  }
  __syncthreads();
  for (int i = start + t; i < end; i += 256) {
    int vv = binned[i];
    int pos = atomicAdd(&cur[vv & (BKT - 1)], 1);
    csr[pos] = vv >> BSH;
  }
}

// ---------------------------------------------------------------------------
// GEMM 1: p(fp16) = x @ Wl ; q(fp16) = x @ Wr + b   (M=100k, K=64, N=64+64)
// ---------------------------------------------------------------------------
__global__ __launch_bounds__(256) void k_gemm1(
    const float* __restrict__ x, const float* __restrict__ Wl,
    const float* __restrict__ Wr, const float* __restrict__ b,
    __half* __restrict__ p, __half* __restrict__ q) {
  __shared__ float sA[64 * 66];
  __shared__ float sW[64 * 128];
  int t = threadIdx.x;
  int n0 = blockIdx.x * 64;

  for (int i = t; i < 64 * 64; i += 256) {
    int r = i >> 6, c = i & 63;
    int n = n0 + r;
    sA[r * 66 + c] = (n < N_NODES) ? x[(size_t)n * 64 + c] : 0.0f;
  }
  for (int f = t; f < 2048; f += 256) {
    int k = f >> 5, c4 = f & 31;
    float4 w = (c4 < 16) ? *(const float4*)&Wl[k * 64 + c4 * 4]
                         : *(const float4*)&Wr[k * 64 + (c4 - 16) * 4];
    *(float4*)&sW[k * 128 + c4 * 4] = w;
  }
  __syncthreads();

  int tx = t & 15;
  int ty = t >> 4;
  float acc[4][8];
#pragma unroll
  for (int i = 0; i < 4; ++i)
#pragma unroll
    for (int j = 0; j < 8; ++j) acc[i][j] = 0.0f;

  for (int k = 0; k < 64; ++k) {
    float4 w0 = *(float4*)&sW[k * 128 + tx * 8];
    float4 w1 = *(float4*)&sW[k * 128 + tx * 8 + 4];
    float wv[8] = {w0.x, w0.y, w0.z, w0.w, w1.x, w1.y, w1.z, w1.w};
#pragma unroll
    for (int i = 0; i < 4; ++i) {
      float a = sA[(ty * 4 + i) * 66 + k];
#pragma unroll
      for (int j = 0; j < 8; ++j) acc[i][j] += a * wv[j];
    }
  }

#pragma unroll
  for (int i = 0; i < 4; ++i) {
    int n = n0 + ty * 4 + i;
    if (n >= N_NODES) break;
    if (tx < 8) {
      int c = tx * 8;
      union { __half h[8]; float4 f; } u;
#pragma unroll
      for (int j = 0; j < 8; ++j) u.h[j] = __float2half(acc[i][j]);
      *(float4*)&p[(size_t)n * 64 + c] = u.f;
    } else {
      int c = (tx - 8) * 8;
      union { __half h[8]; float4 f; } u;
#pragma unroll
      for (int j = 0; j < 8; ++j) u.h[j] = __float2half(acc[i][j] + b[c + j]);
      *(float4*)&q[(size_t)n * 64 + c] = u.f;
    }
  }
}

// ---------------------------------------------------------------------------
// Fuse 1: h[n] = relu(mean_j p1[csr_j] + q1[n]) in place over q1 (fp16).
// 32 lanes per node (half2 lanes), 8 nodes per 256-thread block.
// ---------------------------------------------------------------------------
__global__ __launch_bounds__(256) void k_fuse1(
    const __half2* __restrict__ p1, const int* __restrict__ rowstart,
    const int* __restrict__ cnt, const int* __restrict__ csr,
    __half2* __restrict__ q1h) {
  int t = threadIdx.x;
  int n = blockIdx.x * 8 + (t >> 5);  // 12500*8 = 100000 exact
  int c2 = t & 31;
  int row = rowstart[n];
  int deg = cnt[n];
  float accx = 0.0f, accy = 0.0f;
  int j = 0;
  for (; j + 4 <= deg; j += 4) {
    int s0 = csr[row + j];
    int s1 = csr[row + j + 1];
    int s2 = csr[row + j + 2];
    int s3 = csr[row + j + 3];
    float2 f0 = __half22float2(p1[s0 * 32 + c2]);
    float2 f1 = __half22float2(p1[s1 * 32 + c2]);
    float2 f2 = __half22float2(p1[s2 * 32 + c2]);
    float2 f3 = __half22float2(p1[s3 * 32 + c2]);
    accx += (f0.x + f1.x) + (f2.x + f3.x);
    accy += (f0.y + f1.y) + (f2.y + f3.y);
  }
  for (; j < deg; ++j) {
    float2 f = __half22float2(p1[csr[row + j] * 32 + c2]);
    accx += f.x;
    accy += f.y;
  }
  float inv = 1.0f / fmaxf((float)deg, 1.0f);
  int o = n * 32 + c2;
  float2 qv = __half22float2(q1h[o]);
  float2 r;
  r.x = fmaxf(accx * inv + qv.x, 0.0f);
  r.y = fmaxf(accy * inv + qv.y, 0.0f);
  q1h[o] = __float22half2_rn(r);
}

// ---------------------------------------------------------------------------
// GEMM 2: p2(fp16) = h @ W2l ; q2(fp32) = h @ W2r + b2  (h is fp16)
// ---------------------------------------------------------------------------
__global__ __launch_bounds__(256) void k_gemm2(
    const __half* __restrict__ h, const float* __restrict__ Wl,
    const float* __restrict__ Wr, const float* __restrict__ b,
    __half* __restrict__ p, float* __restrict__ q) {
  __shared__ float sA[128 * 66];
  __shared__ float sW[64 * 32];
  int t = threadIdx.x;
  int n0 = blockIdx.x * 128;

  for (int i = t; i < 128 * 32; i += 256) {  // half2 units
    int r = i >> 5, c2 = i & 31;
    int n = n0 + r;
    float2 v = {0.0f, 0.0f};
    if (n < N_NODES) {
      __half2 hv = *(const __half2*)&h[(size_t)n * 64 + c2 * 2];
      v = __half22float2(hv);
    }
    sA[r * 66 + c2 * 2] = v.x;
    sA[r * 66 + c2 * 2 + 1] = v.y;
  }
  for (int f = t; f < 512; f += 256) {
    int k = f >> 3, c4 = f & 7;
    float4 w = (c4 < 4) ? *(const float4*)&Wl[k * 16 + c4 * 4]
                        : *(const float4*)&Wr[k * 16 + (c4 - 4) * 4];
    *(float4*)&sW[k * 32 + c4 * 4] = w;
  }
  __syncthreads();

  int tx = t & 7;
  int ty = t >> 3;
  float acc[4][4];
#pragma unroll
  for (int i = 0; i < 4; ++i)
#pragma unroll
    for (int j = 0; j < 4; ++j) acc[i][j] = 0.0f;

  for (int k = 0; k < 64; ++k) {
    float4 w = *(float4*)&sW[k * 32 + tx * 4];
    float wv[4] = {w.x, w.y, w.z, w.w};
#pragma unroll
    for (int i = 0; i < 4; ++i) {
      float a = sA[(ty * 4 + i) * 66 + k];
#pragma unroll
      for (int j = 0; j < 4; ++j) acc[i][j] += a * wv[j];
    }
  }

#pragma unroll
  for (int i = 0; i < 4; ++i) {
    int n = n0 + ty * 4 + i;
    if (n >= N_NODES) break;
    if (tx < 4) {
      int c = tx * 4;
      union { __half h[4]; float2 f; } u;
#pragma unroll
      for (int j = 0; j < 4; ++j) u.h[j] = __float2half(acc[i][j]);
      *(float2*)&p[(size_t)n * 16 + c] = u.f;
    } else {
      int c = (tx - 4) * 4;
      float4 o = {acc[i][0] + b[c], acc[i][1] + b[c + 1], acc[i][2] + b[c + 2],
                  acc[i][3] + b[c + 3]};
      *(float4*)&q[(size_t)n * 16 + c] = o;
    }
  }
}

// ---------------------------------------------------------------------------
// Fuse 2: out[n] = mean_j p2[csr_j] + q2[n].
// 8 lanes per node (half2 lanes), 32 nodes per 256-thread block.
// ---------------------------------------------------------------------------
__global__ __launch_bounds__(256) void k_fuse2(
    const __half2* __restrict__ p2, const float* __restrict__ q2,
    const int* __restrict__ rowstart, const int* __restrict__ cnt,
    const int* __restrict__ csr, float* __restrict__ out) {
  int t = threadIdx.x;
  int n = blockIdx.x * 32 + (t >> 3);  // 3125*32 = 100000 exact
  int c2 = t & 7;
  int row = rowstart[n];
  int deg = cnt[n];
  float accx = 0.0f, accy = 0.0f;
  int j = 0;
  for (; j + 4 <= deg; j += 4) {
    int s0 = csr[row + j];
    int s1 = csr[row + j + 1];
    int s2 = csr[row + j + 2];
    int s3 = csr[row + j + 3];
    float2 f0 = __half22float2(p2[s0 * 8 + c2]);
    float2 f1 = __half22float2(p2[s1 * 8 + c2]);
    float2 f2 = __half22float2(p2[s2 * 8 + c2]);
    float2 f3 = __half22float2(p2[s3 * 8 + c2]);
    accx += (f0.x + f1.x) + (f2.x + f3.x);
    accy += (f0.y + f1.y) + (f2.y + f3.y);
  }
  for (; j < deg; ++j) {
    float2 f = __half22float2(p2[csr[row + j] * 8 + c2]);
    accx += f.x;
    accy += f.y;
  }
  float inv = 1.0f / fmaxf((float)deg, 1.0f);
  const float2* q2v = (const float2*)q2;
  float2 qv = q2v[n * 8 + c2];
  float2 r = {accx * inv + qv.x, accy * inv + qv.y};
  *(float2*)&out[(size_t)n * 16 + c2 * 2] = r;
}

extern "C" void kernel_launch(void* const* d_in, const int* in_sizes, int n_in,
                              void* d_out, int out_size, void* d_ws, size_t ws_size,
                              hipStream_t stream) {
  const float* x   = (const float*)d_in[0];
  const int* edge  = (const int*)d_in[1];
  const int* src   = edge;            // edge_index[0]
  const int* dst   = edge + N_EDGES;  // edge_index[1]
  const float* W1l = (const float*)d_in[2];
  const float* b1  = (const float*)d_in[3];
  const float* W1r = (const float*)d_in[4];
  const float* W2l = (const float*)d_in[5];
  const float* b2  = (const float*)d_in[6];
  const float* W2r = (const float*)d_in[7];
  float* out = (float*)d_out;

  // workspace layout (4-byte units; p1 base is 16B aligned)
  int* S        = (int*)d_ws;          // LM = 100096 (bucket count matrix)
  int* bsum     = S + LM;              // 512
  int* R        = bsum + 512;          // LM (scanned bucket offsets)
  int* rowstart = R + LM;              // 100000
  int* cnt      = rowstart + N_NODES;  // 100000
  int* binned   = cnt + N_NODES;       // 1600000
  int* csr      = binned + N_EDGES;    // 1600000
  __half* p1    = (__half*)(csr + N_EDGES);    // 6.4M halves (12.8 MB)
  __half* q1h   = p1 + (size_t)N_NODES * 64;   // 6.4M halves (q1 -> h in place)
  __half* p2    = p1;                          // layer-2 reuse (p1 dead)
  float* q2     = (float*)(p1 + (size_t)N_NODES * 16);  // after p2 (3.2MB)

  // --- CSR build: 6 dispatches, no global atomics ---
  k_count<<<GB, 256, 0, stream>>>(dst, S);
  gscan_a<<<NBM, 256, 0, stream>>>(S, bsum, LM);
  gscan_b<<<1, 512, 0, stream>>>(bsum, NBM);
  gscan_c<<<NBM, 256, 0, stream>>>(S, bsum, R, LM);
  k_binscatter<<<GB, 256, 0, stream>>>(src, dst, R, binned);
  k_finalize<<<NBKT, 256, 0, stream>>>(binned, R, csr, rowstart, cnt);

  // --- layer 1 ---
  k_gemm1<<<(N_NODES + 63) / 64, 256, 0, stream>>>(x, W1l, W1r, b1, p1, q1h);
  k_fuse1<<<N_NODES / 8, 256, 0, stream>>>((const __half2*)p1, rowstart, cnt,
                                           csr, (__half2*)q1h);

  // --- layer 2 ---
  k_gemm2<<<(N_NODES + 127) / 128, 256, 0, stream>>>(q1h, W2l, W2r, b2, p2, q2);
  k_fuse2<<<N_NODES / 32, 256, 0, stream>>>((const __half2*)p2, q2, rowstart,
                                            cnt, csr, out);
}

// Round 7
// 235.038 us; speedup vs baseline: 4.4073x; 1.0689x over previous
//
#include <hip/hip_runtime.h>
#include <hip/hip_fp16.h>

#define N_NODES 100000
#define N_EDGES 1600000
#define IN_C 64
#define HID_C 64
#define OUT_C 16

#define BKT 256        // nodes per dst bucket
#define BSH 8          // dst >> 8 = bucket
#define NBKT 391       // ceil(100000/256)
#define GB 256         // blocks in edge-binning passes
#define EPB 6250       // edges per binning block (256*6250 = 1.6M exact)
#define LM (NBKT*GB)   // bucket count-matrix length = 100096
#define NBM ((LM + 255) / 256)  // 391 scan blocks

// ---------------------------------------------------------------------------
// Pass A1: per-block bucket histogram -> S[bucket*GB + block]. LDS only.
// ---------------------------------------------------------------------------
__global__ __launch_bounds__(256) void k_count(const int* __restrict__ dst,
                                               int* __restrict__ S) {
  __shared__ int h[NBKT];
  for (int i = threadIdx.x; i < NBKT; i += 256) h[i] = 0;
  __syncthreads();
  int base = blockIdx.x * EPB;
  int end = base + EPB;
  for (int e = base + threadIdx.x; e < end; e += 256)
    atomicAdd(&h[dst[e] >> BSH], 1);
  __syncthreads();
  for (int i = threadIdx.x; i < NBKT; i += 256) S[i * GB + blockIdx.x] = h[i];
}

// ---------------------------------------------------------------------------
// Generic 3-kernel exclusive scan (L=100096, nb=391)
// ---------------------------------------------------------------------------
__global__ __launch_bounds__(256) void gscan_a(const int* __restrict__ in,
                                               int* __restrict__ bsum, int L) {
  __shared__ int s[256];
  int i = blockIdx.x * 256 + threadIdx.x;
  s[threadIdx.x] = (i < L) ? in[i] : 0;
  __syncthreads();
  for (int st = 128; st > 0; st >>= 1) {
    if (threadIdx.x < st) s[threadIdx.x] += s[threadIdx.x + st];
    __syncthreads();
  }
  if (threadIdx.x == 0) bsum[blockIdx.x] = s[0];
}

__global__ __launch_bounds__(512) void gscan_b(int* __restrict__ bsum, int nb) {
  __shared__ int s[512];
  int t = threadIdx.x;
  int v = (t < nb) ? bsum[t] : 0;
  s[t] = v;
  __syncthreads();
  for (int st = 1; st < 512; st <<= 1) {
    int a = (t >= st) ? s[t - st] : 0;
    __syncthreads();
    s[t] += a;
    __syncthreads();
  }
  if (t < nb) bsum[t] = s[t] - v;  // exclusive
}

__global__ __launch_bounds__(256) void gscan_c(const int* __restrict__ in,
                                               const int* __restrict__ bsum,
                                               int* __restrict__ outEx, int L) {
  __shared__ int s[256];
  int t = threadIdx.x;
  int i = blockIdx.x * 256 + t;
  int v = (i < L) ? in[i] : 0;
  s[t] = v;
  __syncthreads();
  for (int st = 1; st < 256; st <<= 1) {
    int a = (t >= st) ? s[t - st] : 0;
    __syncthreads();
    s[t] += a;
    __syncthreads();
  }
  if (i < L) outEx[i] = s[t] - v + bsum[blockIdx.x];
}

// ---------------------------------------------------------------------------
// Pass A2: scatter edges into bucket-binned array (frontier writes are
// line-dense, L2-absorbed). Entry packs (src<<8)|dst_local.
// ---------------------------------------------------------------------------
__global__ __launch_bounds__(256) void k_binscatter(
    const int* __restrict__ src, const int* __restrict__ dst,
    const int* __restrict__ R, int* __restrict__ binned) {
  __shared__ int cur[NBKT];
  for (int i = threadIdx.x; i < NBKT; i += 256)
    cur[i] = R[i * GB + blockIdx.x];
  __syncthreads();
  int base = blockIdx.x * EPB;
  int end = base + EPB;
  for (int e = base + threadIdx.x; e < end; e += 256) {
    int d = dst[e];
    int pos = atomicAdd(&cur[d >> BSH], 1);
    binned[pos] = (src[e] << BSH) | (d & (BKT - 1));
  }
}

// ---------------------------------------------------------------------------
// Pass B (fused): per-bucket node histogram -> LDS exclusive scan ->
// rowstart/cnt -> scatter binned segment to CSR. No global atomics.
// ---------------------------------------------------------------------------
__global__ __launch_bounds__(256) void k_finalize(
    const int* __restrict__ binned, const int* __restrict__ R,
    int* __restrict__ csr, int* __restrict__ rowstart, int* __restrict__ cnt) {
  int b = blockIdx.x;
  __shared__ int hcnt[BKT];
  __shared__ int hscan[BKT];
  __shared__ int cur[BKT];
  int t = threadIdx.x;
  hcnt[t] = 0;
  __syncthreads();
  int start = R[b * GB];
  int end = (b == NBKT - 1) ? N_EDGES : R[(b + 1) * GB];
  for (int i = start + t; i < end; i += 256)
    atomicAdd(&hcnt[binned[i] & (BKT - 1)], 1);
  __syncthreads();
  int v = hcnt[t];
  hscan[t] = v;
  __syncthreads();
  for (int st = 1; st < 256; st <<= 1) {
    int a = (t >= st) ? hscan[t - st] : 0;
    __syncthreads();
    hscan[t] += a;
    __syncthreads();
  }
  int rs = start + hscan[t] - v;  // rowstart of node b*BKT + t
  cur[t] = rs;
  int n = (b << BSH) + t;
  if (n < N_NODES) {
    rowstart[n] = rs;
    cnt[n] = v;
  }
  __syncthreads();
  for (int i = start + t; i < end; i += 256) {
    int vv = binned[i];
    int pos = atomicAdd(&cur[vv & (BKT - 1)], 1);
    csr[pos] = vv >> BSH;
  }
}

// ---------------------------------------------------------------------------
// GEMM 1: p(fp16) = x @ Wl ; q(fp16) = x @ Wr + b   (M=100k, K=64, N=64+64)
// Thread (tx,ty): cols tx*4..tx*4+3 of BOTH Wl-half and Wr-half.
// sW float4 reads are 64 consecutive floats across the 16 tx lanes ->
// 2 addresses per bank-group -> 2-way (free). No 4-way conflicts.
// ---------------------------------------------------------------------------
__global__ __launch_bounds__(256) void k_gemm1(
    const float* __restrict__ x, const float* __restrict__ Wl,
    const float* __restrict__ Wr, const float* __restrict__ b,
    __half* __restrict__ p, __half* __restrict__ q) {
  __shared__ float sA[64 * 66];
  __shared__ float sW[64 * 128];  // [k][0..63]=Wl row k, [k][64..127]=Wr row k
  int t = threadIdx.x;
  int n0 = blockIdx.x * 64;

  for (int i = t; i < 64 * 64; i += 256) {
    int r = i >> 6, c = i & 63;
    int n = n0 + r;
    sA[r * 66 + c] = (n < N_NODES) ? x[(size_t)n * 64 + c] : 0.0f;
  }
  for (int f = t; f < 2048; f += 256) {
    int k = f >> 5, c4 = f & 31;
    float4 w = (c4 < 16) ? *(const float4*)&Wl[k * 64 + c4 * 4]
                         : *(const float4*)&Wr[k * 64 + (c4 - 16) * 4];
    *(float4*)&sW[k * 128 + c4 * 4] = w;
  }
  __syncthreads();

  int tx = t & 15;  // col quad
  int ty = t >> 4;  // node group
  float accL[4][4], accR[4][4];
#pragma unroll
  for (int i = 0; i < 4; ++i)
#pragma unroll
    for (int j = 0; j < 4; ++j) { accL[i][j] = 0.0f; accR[i][j] = 0.0f; }

  for (int k = 0; k < 64; ++k) {
    float4 wl = *(float4*)&sW[k * 128 + tx * 4];
    float4 wr = *(float4*)&sW[k * 128 + 64 + tx * 4];
#pragma unroll
    for (int i = 0; i < 4; ++i) {
      float a = sA[(ty * 4 + i) * 66 + k];
      accL[i][0] += a * wl.x; accL[i][1] += a * wl.y;
      accL[i][2] += a * wl.z; accL[i][3] += a * wl.w;
      accR[i][0] += a * wr.x; accR[i][1] += a * wr.y;
      accR[i][2] += a * wr.z; accR[i][3] += a * wr.w;
    }
  }

  float4 bv = *(const float4*)&b[tx * 4];
#pragma unroll
  for (int i = 0; i < 4; ++i) {
    int n = n0 + ty * 4 + i;
    if (n >= N_NODES) break;
    int c = tx * 4;
    union { __half h[4]; float2 f; } up, uq;
#pragma unroll
    for (int j = 0; j < 4; ++j) up.h[j] = __float2half(accL[i][j]);
    uq.h[0] = __float2half(accR[i][0] + bv.x);
    uq.h[1] = __float2half(accR[i][1] + bv.y);
    uq.h[2] = __float2half(accR[i][2] + bv.z);
    uq.h[3] = __float2half(accR[i][3] + bv.w);
    *(float2*)&p[(size_t)n * 64 + c] = up.f;
    *(float2*)&q[(size_t)n * 64 + c] = uq.f;
  }
}

// ---------------------------------------------------------------------------
// Fuse 1: h[n] = relu(mean_j p1[csr_j] + q1[n]) in place over q1 (fp16).
// float4 gathers: 8 lanes per node (16B each = 128B row), 32 nodes/block.
// ---------------------------------------------------------------------------
__global__ __launch_bounds__(256) void k_fuse1(
    const float4* __restrict__ p1, const int* __restrict__ rowstart,
    const int* __restrict__ cnt, const int* __restrict__ csr,
    float4* __restrict__ q1h) {
  int t = threadIdx.x;
  int n = blockIdx.x * 32 + (t >> 3);  // 3125*32 = 100000 exact
  int c4 = t & 7;
  int row = rowstart[n];
  int deg = cnt[n];
  float acc[8];
#pragma unroll
  for (int m = 0; m < 8; ++m) acc[m] = 0.0f;
  int j = 0;
  for (; j + 4 <= deg; j += 4) {
    int s0 = csr[row + j];
    int s1 = csr[row + j + 1];
    int s2 = csr[row + j + 2];
    int s3 = csr[row + j + 3];
    float4 a0 = p1[s0 * 8 + c4];
    float4 a1 = p1[s1 * 8 + c4];
    float4 a2 = p1[s2 * 8 + c4];
    float4 a3 = p1[s3 * 8 + c4];
    const __half2* h0 = (const __half2*)&a0;
    const __half2* h1 = (const __half2*)&a1;
    const __half2* h2 = (const __half2*)&a2;
    const __half2* h3 = (const __half2*)&a3;
#pragma unroll
    for (int m = 0; m < 4; ++m) {
      float2 f0 = __half22float2(h0[m]);
      float2 f1 = __half22float2(h1[m]);
      float2 f2 = __half22float2(h2[m]);
      float2 f3 = __half22float2(h3[m]);
      acc[2 * m]     += (f0.x + f1.x) + (f2.x + f3.x);
      acc[2 * m + 1] += (f0.y + f1.y) + (f2.y + f3.y);
    }
  }
  for (; j < deg; ++j) {
    float4 a = p1[csr[row + j] * 8 + c4];
    const __half2* h = (const __half2*)&a;
#pragma unroll
    for (int m = 0; m < 4; ++m) {
      float2 f = __half22float2(h[m]);
      acc[2 * m] += f.x;
      acc[2 * m + 1] += f.y;
    }
  }
  float inv = 1.0f / fmaxf((float)deg, 1.0f);
  int o = n * 8 + c4;
  float4 qv = q1h[o];
  __half2* qh = (__half2*)&qv;
  float4 r;
  __half2* rh = (__half2*)&r;
#pragma unroll
  for (int m = 0; m < 4; ++m) {
    float2 f = __half22float2(qh[m]);
    float2 s;
    s.x = fmaxf(acc[2 * m] * inv + f.x, 0.0f);
    s.y = fmaxf(acc[2 * m + 1] * inv + f.y, 0.0f);
    rh[m] = __float22half2_rn(s);
  }
  q1h[o] = r;
}

// ---------------------------------------------------------------------------
// GEMM 2: p2(fp16) = h @ W2l ; q2(fp32) = h @ W2r + b2  (h is fp16)
// ---------------------------------------------------------------------------
__global__ __launch_bounds__(256) void k_gemm2(
    const __half* __restrict__ h, const float* __restrict__ Wl,
    const float* __restrict__ Wr, const float* __restrict__ b,
    __half* __restrict__ p, float* __restrict__ q) {
  __shared__ float sA[128 * 66];
  __shared__ float sW[64 * 32];
  int t = threadIdx.x;
  int n0 = blockIdx.x * 128;

  for (int i = t; i < 128 * 32; i += 256) {  // half2 units
    int r = i >> 5, c2 = i & 31;
    int n = n0 + r;
    float2 v = {0.0f, 0.0f};
    if (n < N_NODES) {
      __half2 hv = *(const __half2*)&h[(size_t)n * 64 + c2 * 2];
      v = __half22float2(hv);
    }
    sA[r * 66 + c2 * 2] = v.x;
    sA[r * 66 + c2 * 2 + 1] = v.y;
  }
  for (int f = t; f < 512; f += 256) {
    int k = f >> 3, c4 = f & 7;
    float4 w = (c4 < 4) ? *(const float4*)&Wl[k * 16 + c4 * 4]
                        : *(const float4*)&Wr[k * 16 + (c4 - 4) * 4];
    *(float4*)&sW[k * 32 + c4 * 4] = w;
  }
  __syncthreads();

  int tx = t & 7;
  int ty = t >> 3;
  float acc[4][4];
#pragma unroll
  for (int i = 0; i < 4; ++i)
#pragma unroll
    for (int j = 0; j < 4; ++j) acc[i][j] = 0.0f;

  for (int k = 0; k < 64; ++k) {
    float4 w = *(float4*)&sW[k * 32 + tx * 4];
#pragma unroll
    for (int i = 0; i < 4; ++i) {
      float a = sA[(ty * 4 + i) * 66 + k];
      acc[i][0] += a * w.x; acc[i][1] += a * w.y;
      acc[i][2] += a * w.z; acc[i][3] += a * w.w;
    }
  }

#pragma unroll
  for (int i = 0; i < 4; ++i) {
    int n = n0 + ty * 4 + i;
    if (n >= N_NODES) break;
    if (tx < 4) {
      int c = tx * 4;
      union { __half h[4]; float2 f; } u;
#pragma unroll
      for (int j = 0; j < 4; ++j) u.h[j] = __float2half(acc[i][j]);
      *(float2*)&p[(size_t)n * 16 + c] = u.f;
    } else {
      int c = (tx - 4) * 4;
      float4 o = {acc[i][0] + b[c], acc[i][1] + b[c + 1], acc[i][2] + b[c + 2],
                  acc[i][3] + b[c + 3]};
      *(float4*)&q[(size_t)n * 16 + c] = o;
    }
  }
}

// ---------------------------------------------------------------------------
// Fuse 2: out[n] = mean_j p2[csr_j] + q2[n].
// 8 lanes per node (half2 lanes), 32 nodes per 256-thread block.
// ---------------------------------------------------------------------------
__global__ __launch_bounds__(256) void k_fuse2(
    const __half2* __restrict__ p2, const float* __restrict__ q2,
    const int* __restrict__ rowstart, const int* __restrict__ cnt,
    const int* __restrict__ csr, float* __restrict__ out) {
  int t = threadIdx.x;
  int n = blockIdx.x * 32 + (t >> 3);  // 3125*32 = 100000 exact
  int c2 = t & 7;
  int row = rowstart[n];
  int deg = cnt[n];
  float accx = 0.0f, accy = 0.0f;
  int j = 0;
  for (; j + 4 <= deg; j += 4) {
    int s0 = csr[row + j];
    int s1 = csr[row + j + 1];
    int s2 = csr[row + j + 2];
    int s3 = csr[row + j + 3];
    float2 f0 = __half22float2(p2[s0 * 8 + c2]);
    float2 f1 = __half22float2(p2[s1 * 8 + c2]);
    float2 f2 = __half22float2(p2[s2 * 8 + c2]);
    float2 f3 = __half22float2(p2[s3 * 8 + c2]);
    accx += (f0.x + f1.x) + (f2.x + f3.x);
    accy += (f0.y + f1.y) + (f2.y + f3.y);
  }
  for (; j < deg; ++j) {
    float2 f = __half22float2(p2[csr[row + j] * 8 + c2]);
    accx += f.x;
    accy += f.y;
  }
  float inv = 1.0f / fmaxf((float)deg, 1.0f);
  const float2* q2v = (const float2*)q2;
  float2 qv = q2v[n * 8 + c2];
  float2 r = {accx * inv + qv.x, accy * inv + qv.y};
  *(float2*)&out[(size_t)n * 16 + c2 * 2] = r;
}

extern "C" void kernel_launch(void* const* d_in, const int* in_sizes, int n_in,
                              void* d_out, int out_size, void* d_ws, size_t ws_size,
                              hipStream_t stream) {
  const float* x   = (const float*)d_in[0];
  const int* edge  = (const int*)d_in[1];
  const int* src   = edge;            // edge_index[0]
  const int* dst   = edge + N_EDGES;  // edge_index[1]
  const float* W1l = (const float*)d_in[2];
  const float* b1  = (const float*)d_in[3];
  const float* W1r = (const float*)d_in[4];
  const float* W2l = (const float*)d_in[5];
  const float* b2  = (const float*)d_in[6];
  const float* W2r = (const float*)d_in[7];
  float* out = (float*)d_out;

  // workspace layout (4-byte units; p1 base is 16B aligned)
  int* S        = (int*)d_ws;          // LM = 100096 (bucket count matrix)
  int* bsum     = S + LM;              // 512
  int* R        = bsum + 512;          // LM (scanned bucket offsets)
  int* rowstart = R + LM;              // 100000
  int* cnt      = rowstart + N_NODES;  // 100000
  int* binned   = cnt + N_NODES;       // 1600000
  int* csr      = binned + N_EDGES;    // 1600000
  __half* p1    = (__half*)(csr + N_EDGES);    // 6.4M halves (12.8 MB)
  __half* q1h   = p1 + (size_t)N_NODES * 64;   // 6.4M halves (q1 -> h in place)
  __half* p2    = p1;                          // layer-2 reuse (p1 dead)
  float* q2     = (float*)(p1 + (size_t)N_NODES * 16);  // after p2 (3.2MB)

  // --- CSR build: 6 dispatches, no global atomics ---
  k_count<<<GB, 256, 0, stream>>>(dst, S);
  gscan_a<<<NBM, 256, 0, stream>>>(S, bsum, LM);
  gscan_b<<<1, 512, 0, stream>>>(bsum, NBM);
  gscan_c<<<NBM, 256, 0, stream>>>(S, bsum, R, LM);
  k_binscatter<<<GB, 256, 0, stream>>>(src, dst, R, binned);
  k_finalize<<<NBKT, 256, 0, stream>>>(binned, R, csr, rowstart, cnt);

  // --- layer 1 ---
  k_gemm1<<<(N_NODES + 63) / 64, 256, 0, stream>>>(x, W1l, W1r, b1, p1, q1h);
  k_fuse1<<<N_NODES / 32, 256, 0, stream>>>((const float4*)p1, rowstart, cnt,
                                            csr, (float4*)q1h);

  // --- layer 2 ---
  k_gemm2<<<(N_NODES + 127) / 128, 256, 0, stream>>>(q1h, W2l, W2r, b2, p2, q2);
  k_fuse2<<<N_NODES / 32, 256, 0, stream>>>((const __half2*)p2, q2, rowstart,
                                            cnt, csr, out);
}